// Round 1
// baseline (327.035 us; speedup 1.0000x reference)
//
#include <hip/hip_runtime.h>
#include <hip/hip_bf16.h>

#define D_MODEL 512
#define BATCH 4
#define SEQ 2048
#define ROWS (BATCH*SEQ)   // 8192

typedef unsigned short u16;
typedef short bf16x8 __attribute__((ext_vector_type(8)));
typedef float f32x4 __attribute__((ext_vector_type(4)));

__device__ __forceinline__ float bf2f(u16 u) {
    union { unsigned int i; float f; } v;
    v.i = ((unsigned int)u) << 16;
    return v.f;
}
__device__ __forceinline__ u16 f2bf(float f) {
    union { float f; unsigned int i; } v;
    v.f = f;
    unsigned int x = v.i;
    unsigned int r = (x >> 16) & 1u;
    x += 0x7fffu + r;           // round-to-nearest-even
    return (u16)(x >> 16);
}

// ---------------- split fp32 -> (hi, lo) bf16 ----------------
__global__ __launch_bounds__(256)
void split_f32_kernel(const float* __restrict__ in, u16* __restrict__ h,
                      u16* __restrict__ l, int n) {
    int i = (blockIdx.x * 256 + threadIdx.x) * 4;
    if (i >= n) return;
    float4 v = *(const float4*)(in + i);
    u16 hh[4], ll[4];
    float vv[4] = { v.x, v.y, v.z, v.w };
    #pragma unroll
    for (int j = 0; j < 4; ++j) {
        u16 hi = f2bf(vv[j]);
        hh[j] = hi;
        ll[j] = f2bf(vv[j] - bf2f(hi));
    }
    *(ushort4*)(h + i) = make_ushort4(hh[0], hh[1], hh[2], hh[3]);
    *(ushort4*)(l + i) = make_ushort4(ll[0], ll[1], ll[2], ll[3]);
}

// ---------------- GEMM: C[m,n] = scale * sum_k A[m,k]*B[n,k] + bias[n] ----------------
// A, B given as (hi, lo) bf16 pairs; fp32 accumulate via 3 MFMAs (hh, hl, lh).
// Output: either fp32 (outF) or split bf16 (outH/outL), optionally transposed
// (v path: [B][512][2048] layout).
__global__ __launch_bounds__(256, 2)
void gemm_bt(const u16* __restrict__ Ah, const u16* __restrict__ Al,
             const u16* __restrict__ Bh, const u16* __restrict__ Bl,
             const float* __restrict__ bias,
             float* __restrict__ outF, u16* __restrict__ outH, u16* __restrict__ outL,
             int K, int lda, int ldb, int ldc,
             long aStride, long bStride, long cStride,
             float scale, int transposeOut)
{
    __shared__ u16 lds[4 * 128 * 40];   // Ah, Al, Bh, Bl tiles [128][32] padded to 40
    const int tid  = threadIdx.x;
    const int lane = tid & 63;
    const int wave = tid >> 6;
    const int wr = wave >> 1, wc = wave & 1;
    const int bx = blockIdx.x, by = blockIdx.y, bz = blockIdx.z;

    const long aBase = (long)bz * aStride + (long)(bx * 128) * lda;
    const long bBase = (long)bz * bStride + (long)(by * 128) * ldb;

    f32x4 acc[4][4] = {};

    const int sr = tid >> 2;          // 0..63
    const int sc = (tid & 3) * 8;     // 0,8,16,24
    const int frow = lane & 15;
    const int kofs = (lane >> 4) * 8;

    for (int k0 = 0; k0 < K; k0 += 32) {
        __syncthreads();
        {
            const u16* s0 = Ah + aBase + k0;
            const u16* s1 = Al + aBase + k0;
            const u16* s2 = Bh + bBase + k0;
            const u16* s3 = Bl + bBase + k0;
            *(uint4*)&lds[(0*128 + sr      )*40 + sc] = *(const uint4*)(s0 + (long)sr*lda + sc);
            *(uint4*)&lds[(0*128 + sr + 64 )*40 + sc] = *(const uint4*)(s0 + (long)(sr+64)*lda + sc);
            *(uint4*)&lds[(1*128 + sr      )*40 + sc] = *(const uint4*)(s1 + (long)sr*lda + sc);
            *(uint4*)&lds[(1*128 + sr + 64 )*40 + sc] = *(const uint4*)(s1 + (long)(sr+64)*lda + sc);
            *(uint4*)&lds[(2*128 + sr      )*40 + sc] = *(const uint4*)(s2 + (long)sr*ldb + sc);
            *(uint4*)&lds[(2*128 + sr + 64 )*40 + sc] = *(const uint4*)(s2 + (long)(sr+64)*ldb + sc);
            *(uint4*)&lds[(3*128 + sr      )*40 + sc] = *(const uint4*)(s3 + (long)sr*ldb + sc);
            *(uint4*)&lds[(3*128 + sr + 64 )*40 + sc] = *(const uint4*)(s3 + (long)(sr+64)*ldb + sc);
        }
        __syncthreads();

        bf16x8 aH[4], aL[4], bH[4], bL[4];
        #pragma unroll
        for (int m = 0; m < 4; ++m) {
            int rA = wr*64 + m*16 + frow;
            aH[m] = *(const bf16x8*)&lds[(0*128 + rA)*40 + kofs];
            aL[m] = *(const bf16x8*)&lds[(1*128 + rA)*40 + kofs];
            int rB = wc*64 + m*16 + frow;
            bH[m] = *(const bf16x8*)&lds[(2*128 + rB)*40 + kofs];
            bL[m] = *(const bf16x8*)&lds[(3*128 + rB)*40 + kofs];
        }
        #pragma unroll
        for (int m = 0; m < 4; ++m)
            #pragma unroll
            for (int n = 0; n < 4; ++n) {
                acc[m][n] = __builtin_amdgcn_mfma_f32_16x16x32_bf16(aH[m], bH[n], acc[m][n], 0, 0, 0);
                acc[m][n] = __builtin_amdgcn_mfma_f32_16x16x32_bf16(aH[m], bL[n], acc[m][n], 0, 0, 0);
                acc[m][n] = __builtin_amdgcn_mfma_f32_16x16x32_bf16(aL[m], bH[n], acc[m][n], 0, 0, 0);
            }
    }

    // epilogue: C/D layout col=lane&15, row=(lane>>4)*4+reg  [m89-verified]
    const int rr = (lane >> 4) * 4;
    #pragma unroll
    for (int n = 0; n < 4; ++n) {
        int colL = by*128 + wc*64 + n*16 + frow;
        float bv_ = bias ? bias[colL] : 0.0f;
        #pragma unroll
        for (int m = 0; m < 4; ++m) {
            #pragma unroll
            for (int j = 0; j < 4; ++j) {
                int rowL = bx*128 + wr*64 + m*16 + rr + j;
                float val = acc[m][n][j] * scale + bv_;
                if (outF) {
                    outF[(long)bz*cStride + (long)rowL*ldc + colL] = val;
                } else if (transposeOut) {
                    // v path: [B][512][2048]; rowL is global (b*2048 + m)
                    int b = rowL >> 11;
                    int mrow = rowL & 2047;
                    long idx = (long)b*1048576 + (long)colL*2048 + mrow;
                    u16 h = f2bf(val);
                    outH[idx] = h;
                    outL[idx] = f2bf(val - bf2f(h));
                } else {
                    long idx = (long)bz*cStride + (long)rowL*ldc + colL;
                    u16 h = f2bf(val);
                    outH[idx] = h;
                    outL[idx] = f2bf(val - bf2f(h));
                }
            }
        }
    }
}

// ---------------- row softmax over 2048, in-place on (hi, lo) pair ----------------
__global__ __launch_bounds__(256)
void softmax_kernel(u16* __restrict__ sh, u16* __restrict__ sl)
{
    const long base = (long)blockIdx.x * 2048;
    const int tid = threadIdx.x;
    const int lane = tid & 63, wave = tid >> 6;
    u16* hp = sh + base + tid * 8;
    u16* lp = sl + base + tid * 8;
    bf16x8 hv = *(const bf16x8*)hp;
    bf16x8 lv = *(const bf16x8*)lp;
    float s[8];
    #pragma unroll
    for (int j = 0; j < 8; ++j) s[j] = bf2f((u16)hv[j]) + bf2f((u16)lv[j]);

    float mx = s[0];
    #pragma unroll
    for (int j = 1; j < 8; ++j) mx = fmaxf(mx, s[j]);
    #pragma unroll
    for (int off = 32; off >= 1; off >>= 1) mx = fmaxf(mx, __shfl_xor(mx, off));
    __shared__ float red[8];
    if (lane == 0) red[wave] = mx;
    __syncthreads();
    mx = fmaxf(fmaxf(red[0], red[1]), fmaxf(red[2], red[3]));

    float e[8], sum = 0.f;
    #pragma unroll
    for (int j = 0; j < 8; ++j) { e[j] = __expf(s[j] - mx); sum += e[j]; }
    #pragma unroll
    for (int off = 32; off >= 1; off >>= 1) sum += __shfl_xor(sum, off);
    if (lane == 0) red[4 + wave] = sum;
    __syncthreads();
    sum = red[4] + red[5] + red[6] + red[7];
    float inv = 1.0f / sum;

    bf16x8 ho, lo_;
    #pragma unroll
    for (int j = 0; j < 8; ++j) {
        float pv = e[j] * inv;
        u16 h = f2bf(pv);
        ho[j] = (short)h;
        lo_[j] = (short)f2bf(pv - bf2f(h));
    }
    *(bf16x8*)hp = ho;
    *(bf16x8*)lp = lo_;
}

extern "C" void kernel_launch(void* const* d_in, const int* in_sizes, int n_in,
                              void* d_out, int out_size, void* d_ws, size_t ws_size,
                              hipStream_t stream)
{
    const float* x  = (const float*)d_in[0];
    const float* Wq = (const float*)d_in[1];
    const float* bq = (const float*)d_in[2];
    const float* Wk = (const float*)d_in[3];
    const float* bk = (const float*)d_in[4];
    const float* Wv = (const float*)d_in[5];
    const float* bv = (const float*)d_in[6];
    const float* Wo = (const float*)d_in[7];
    const float* bo = (const float*)d_in[8];

    char* p = (char*)d_ws;
    auto alloc = [&](size_t bytes) { char* r = p; p += (bytes + 255) & ~(size_t)255; return r; };

    const size_t XE = (size_t)ROWS * D_MODEL;     // 4,194,304
    const size_t WE = (size_t)D_MODEL * D_MODEL;  // 262,144
    const size_t SE = (size_t)BATCH * SEQ * SEQ;  // 16,777,216

    u16* xh  = (u16*)alloc(XE * 2);
    u16* xl  = (u16*)alloc(XE * 2);
    u16* wqh = (u16*)alloc(WE * 2);
    u16* wql = (u16*)alloc(WE * 2);
    u16* wkh = (u16*)alloc(WE * 2);
    u16* wkl = (u16*)alloc(WE * 2);
    u16* wvh = (u16*)alloc(WE * 2);
    u16* wvl = (u16*)alloc(WE * 2);
    u16* woh = (u16*)alloc(WE * 2);
    u16* wol = (u16*)alloc(WE * 2);
    u16* qh  = (u16*)alloc(XE * 2);
    u16* ql  = (u16*)alloc(XE * 2);
    u16* kh  = (u16*)alloc(XE * 2);
    u16* kl  = (u16*)alloc(XE * 2);
    u16* vTh = (u16*)alloc(XE * 2);
    u16* vTl = (u16*)alloc(XE * 2);
    u16* sh  = (u16*)alloc(SE * 2);
    u16* sl  = (u16*)alloc(SE * 2);
    // att (split) aliases x's split buffers — x is dead after the V projection
    u16* ath = xh;
    u16* atl = xl;

    // 1. splits
    split_f32_kernel<<<XE / 1024, 256, 0, stream>>>(x,  xh,  xl,  (int)XE);
    split_f32_kernel<<<WE / 1024, 256, 0, stream>>>(Wq, wqh, wql, (int)WE);
    split_f32_kernel<<<WE / 1024, 256, 0, stream>>>(Wk, wkh, wkl, (int)WE);
    split_f32_kernel<<<WE / 1024, 256, 0, stream>>>(Wv, wvh, wvl, (int)WE);
    split_f32_kernel<<<WE / 1024, 256, 0, stream>>>(Wo, woh, wol, (int)WE);

    // 2. q = x@Wq^T + bq ; k = x@Wk^T + bk ; v = x@Wv^T + bv (transposed store)
    gemm_bt<<<dim3(64, 4, 1), 256, 0, stream>>>(xh, xl, wqh, wql, bq,
        nullptr, qh, ql, 512, 512, 512, 512, 0, 0, 0, 1.0f, 0);
    gemm_bt<<<dim3(64, 4, 1), 256, 0, stream>>>(xh, xl, wkh, wkl, bk,
        nullptr, kh, kl, 512, 512, 512, 512, 0, 0, 0, 1.0f, 0);
    gemm_bt<<<dim3(64, 4, 1), 256, 0, stream>>>(xh, xl, wvh, wvl, bv,
        nullptr, vTh, vTl, 512, 512, 512, 512, 0, 0, 0, 1.0f, 1);

    // 3. scores = q@k^T * 1/sqrt(512)   [per batch]
    gemm_bt<<<dim3(16, 16, 4), 256, 0, stream>>>(qh, ql, kh, kl, nullptr,
        nullptr, sh, sl, 512, 512, 512, 2048,
        (long)SEQ * 512, (long)SEQ * 512, (long)SEQ * SEQ,
        0.044194173824159216f, 0);

    // 4. softmax rows (in-place on hi/lo pair)
    softmax_kernel<<<ROWS, 256, 0, stream>>>(sh, sl);

    // 5. att = p @ v   [per batch; B operand = vT]
    gemm_bt<<<dim3(16, 4, 4), 256, 0, stream>>>(sh, sl, vTh, vTl, nullptr,
        nullptr, ath, atl, 2048, 2048, 2048, 512,
        (long)SEQ * SEQ, (long)512 * SEQ, (long)SEQ * 512,
        1.0f, 0);

    // 6. out = att @ Wo^T + bo  (fp32 to d_out)
    gemm_bt<<<dim3(64, 4, 1), 256, 0, stream>>>(ath, atl, woh, wol, bo,
        (float*)d_out, nullptr, nullptr, 512, 512, 512, 512,
        0, 0, 0, 1.0f, 0);
}